// Round 8
// baseline (715.582 us; speedup 1.0000x reference)
//
#include <hip/hip_runtime.h>
#include <math.h>

// Problem constants
#define BB 4
#define TT 2048
#define DD 1024
#define HH 16
#define QKD 64
#define MM (BB*TT)          // 8192
#define NN 1024             // H*QK == D
#define KK 1024

typedef unsigned short u16;
typedef __attribute__((ext_vector_type(8))) short short8;   // 8 bf16 = 4 VGPRs
typedef __attribute__((ext_vector_type(4))) float float4v;  // MFMA C/D

// fp32 -> bf16 round-to-nearest-even
__device__ __forceinline__ u16 f2bf(float f) {
    union { float f; unsigned u; } v; v.f = f;
    unsigned r = (v.u + 0x7FFFu + ((v.u >> 16) & 1u)) >> 16;
    return (u16)r;
}

// async global->LDS, 16B per lane; LDS dest = wave-uniform base + lane*16
typedef __attribute__((address_space(3))) unsigned lds_u32_t;
typedef __attribute__((address_space(1))) const unsigned glb_u32_t;
__device__ __forceinline__ void gl2lds16(const u16* g, u16* l) {
    __builtin_amdgcn_global_load_lds((glb_u32_t*)g, (lds_u32_t*)l, 16, 0, 0);
}

// ---------------------------------------------------------------------------
// fp32 -> bf16 cast for activations (q, kv)
// ---------------------------------------------------------------------------
__global__ __launch_bounds__(256) void acast_kernel(
    const float* __restrict__ a, const float* __restrict__ b,
    u16* __restrict__ da, u16* __restrict__ db)
{
    const float* s = blockIdx.y ? b : a;
    u16* d = blockIdx.y ? db : da;
    size_t i = ((size_t)blockIdx.x * 256 + threadIdx.x) * 4;
    float4 v = *(const float4*)&s[i];
    ushort4 o = { f2bf(v.x), f2bf(v.y), f2bf(v.z), f2bf(v.w) };
    *(ushort4*)&d[i] = o;
}

// ---------------------------------------------------------------------------
// Weight transpose + cast: W[K][N] fp32 -> Wt[N][K] bf16, z selects matrix
// ---------------------------------------------------------------------------
__global__ __launch_bounds__(256) void wt_kernel(
    const float* __restrict__ Wq, const float* __restrict__ Wk,
    const float* __restrict__ Wv, const float* __restrict__ Wo,
    u16* __restrict__ dstbase)
{
    const int z = blockIdx.z;
    const float* src = (z == 0) ? Wq : (z == 1) ? Wk : (z == 2) ? Wv : Wo;
    u16* out = dstbase + (size_t)z * (KK * NN);
    const int bi = blockIdx.y, bj = blockIdx.x;
    __shared__ float tile[64][65];
    const int t = threadIdx.x;
    #pragma unroll
    for (int p = 0; p < 4; p++) {
        int idx = p * 256 + t;
        int r = idx >> 4, c4 = (idx & 15) << 2;
        float4 v = *(const float4*)&src[(size_t)(bi * 64 + r) * NN + bj * 64 + c4];
        tile[r][c4 + 0] = v.x; tile[r][c4 + 1] = v.y;
        tile[r][c4 + 2] = v.z; tile[r][c4 + 3] = v.w;
    }
    __syncthreads();
    #pragma unroll
    for (int p = 0; p < 4; p++) {
        int idx = p * 256 + t;
        int rn = idx >> 4, c4 = (idx & 15) << 2;
        ushort4 o = { f2bf(tile[c4 + 0][rn]), f2bf(tile[c4 + 1][rn]),
                      f2bf(tile[c4 + 2][rn]), f2bf(tile[c4 + 3][rn]) };
        *(ushort4*)&out[(size_t)(bj * 64 + rn) * KK + bi * 64 + c4] = o;
    }
}

// ---------------------------------------------------------------------------
// bf16 MFMA GEMM main loop (m97 structure). See round-3 notes.
// ---------------------------------------------------------------------------
__device__ __forceinline__ void gemm_mainloop(
    const u16* __restrict__ A, const u16* __restrict__ Bt,
    int m0, int n0, u16* As, u16* Bs, float4v (&acc)[4][4])
{
    const int tid = threadIdx.x;
    const int wave = tid >> 6, lane = tid & 63;
    const int l15 = lane & 15, lg = lane >> 4;
    const int wm = wave >> 1, wn = wave & 1;

    const int lr = lane >> 3;
    const int lc = lane & 7;

    for (int k0 = 0; k0 < KK; k0 += 64) {
        #pragma unroll
        for (int i = 0; i < 4; i++) {
            int chunk = wave * 4 + i;
            int row = chunk * 8 + lr;
            int gcb = lc ^ (row & 7);
            gl2lds16(A  + (size_t)(m0 + row) * KK + k0 + gcb * 8, As + chunk * 512);
            gl2lds16(Bt + (size_t)(n0 + row) * KK + k0 + gcb * 8, Bs + chunk * 512);
        }
        __syncthreads();

        short8 af[2][4], bf[2][4];
        #pragma unroll
        for (int kc = 0; kc < 2; kc++) {
            #pragma unroll
            for (int x = 0; x < 4; x++) {
                int ra = wm * 64 + x * 16 + l15;
                int sa = (kc * 4 + lg) ^ (ra & 7);
                af[kc][x] = *(const short8*)(As + ra * 64 + sa * 8);
                int rb = wn * 64 + x * 16 + l15;
                int sb = (kc * 4 + lg) ^ (rb & 7);
                bf[kc][x] = *(const short8*)(Bs + rb * 64 + sb * 8);
            }
        }
        #pragma unroll
        for (int mi = 0; mi < 4; mi++)
            #pragma unroll
            for (int nj = 0; nj < 4; nj++) {
                acc[mi][nj] = __builtin_amdgcn_mfma_f32_16x16x32_bf16(af[0][mi], bf[0][nj], acc[mi][nj], 0, 0, 0);
                acc[mi][nj] = __builtin_amdgcn_mfma_f32_16x16x32_bf16(af[1][mi], bf[1][nj], acc[mi][nj], 0, 0, 0);
            }
        __syncthreads();
    }
}

// ---------------------------------------------------------------------------
// QKV projection GEMM. z is now a kernel ARGUMENT (separate dispatches) so
// rocprof gives per-z FETCH/WRITE — discriminates external-traffic bleed
// (z=0 carries it all) vs kernel-caused traffic (spread evenly).
// ---------------------------------------------------------------------------
#define BSTR 80   // u16 row stride of bounce tile: 16B-aligned, 2-way banks

__global__ __launch_bounds__(256) void qkv_gemm(
    const u16* __restrict__ qb, const u16* __restrict__ kvb,
    const u16* __restrict__ Wt,
    const float* __restrict__ bq, const float* __restrict__ bk, const float* __restrict__ bv,
    const int* __restrict__ qpos, const int* __restrict__ kpos,
    const float* __restrict__ q_scale, const float* __restrict__ k_scale,
    u16* __restrict__ qh, u16* __restrict__ kh, u16* __restrict__ vh, int z)
{
    __shared__ u16 smem[4 * 64 * BSTR];   // 40960 B; mainloop uses first 32 KB
    u16* As = smem;
    u16* Bs = smem + 128 * 64;

    const u16* A        = (z == 0) ? qb : kvb;
    const u16* B        = Wt + (size_t)z * (KK * NN);
    const float* bias   = (z == 0) ? bq : (z == 1) ? bk : bv;
    const float* scl    = (z == 0) ? q_scale : k_scale;
    const int* pos_arr  = (z == 0) ? qpos : kpos;

    const int m0 = blockIdx.y * 128, n0 = blockIdx.x * 128;

    float4v acc[4][4];
    #pragma unroll
    for (int i = 0; i < 4; i++)
        #pragma unroll
        for (int j = 0; j < 4; j++) acc[i][j] = (float4v){0.f, 0.f, 0.f, 0.f};

    gemm_mainloop(A, B, m0, n0, As, Bs, acc);
    // mainloop ends with __syncthreads(): smem is free; each wave now uses
    // only its private bounce tile (no further barriers needed).

    const int tid = threadIdx.x;
    const int lane = tid & 63, wave = tid >> 6;
    const int l15 = lane & 15, lg = lane >> 4;
    const int wm = wave >> 1, wn = wave & 1;
    const int h = (n0 >> 6) + wn;
    const int b0 = m0 >> 11;
    const int tq0 = (m0 & 2047) + wm * 64;

    u16* myT = smem + wave * (64 * BSTR);

    float bia[4];
    #pragma unroll
    for (int nj = 0; nj < 4; nj++)
        bia[nj] = bias[h * 64 + nj * 16 + l15];

    if (z < 2) {
        float sc[4];
        #pragma unroll
        for (int nj = 0; nj < 4; nj++) sc[nj] = 1.0f + scl[nj * 16 + l15];
        float invts[2];
        #pragma unroll
        for (int p = 0; p < 2; p++)
            invts[p] = powf(10000.0f, -(float)(p * 16 + l15) * (1.0f / 32.0f));
        const float QMUL = 0.125f * 1.44269504088896340736f;

        #pragma unroll
        for (int mi = 0; mi < 4; mi++) {
            #pragma unroll
            for (int r = 0; r < 4; r++) {
                const int mrow = mi * 16 + lg * 4 + r;
                const int t = tq0 + mrow;
                float v[4];
                #pragma unroll
                for (int nj = 0; nj < 4; nj++) v[nj] = acc[mi][nj][r] + bia[nj];

                float ss = v[0]*v[0] + v[1]*v[1] + v[2]*v[2] + v[3]*v[3];
                ss += __shfl_xor(ss, 1);
                ss += __shfl_xor(ss, 2);
                ss += __shfl_xor(ss, 4);
                ss += __shfl_xor(ss, 8);
                float rn = rsqrtf(ss * (1.0f / 64.0f) + 1e-6f);
                #pragma unroll
                for (int nj = 0; nj < 4; nj++) v[nj] = v[nj] * rn * sc[nj];

                const float pos = (float)pos_arr[b0 * TT + t];
                #pragma unroll
                for (int p = 0; p < 2; p++) {
                    float ang = pos * invts[p];
                    float s = sinf(ang), c = cosf(ang);
                    float x1 = v[p], x2 = v[p + 2];
                    v[p]     = x1 * c - x2 * s;
                    v[p + 2] = x2 * c + x1 * s;
                }
                if (z == 0) {
                    #pragma unroll
                    for (int nj = 0; nj < 4; nj++) v[nj] *= QMUL;
                }
                #pragma unroll
                for (int nj = 0; nj < 4; nj++)
                    myT[mrow * BSTR + nj * 16 + l15] = f2bf(v[nj]);
            }
        }
    } else {
        #pragma unroll
        for (int mi = 0; mi < 4; mi++)
            #pragma unroll
            for (int r = 0; r < 4; r++) {
                const int mrow = mi * 16 + lg * 4 + r;
                #pragma unroll
                for (int nj = 0; nj < 4; nj++)
                    myT[mrow * BSTR + nj * 16 + l15] = f2bf(acc[mi][nj][r] + bia[nj]);
            }
    }

    // wide writeback: full 64B-line coverage per store instruction
    u16* dstb = (z == 0) ? qh : (z == 1) ? kh : vh;
    const int lrow = lane >> 3, lchk = lane & 7;
    u16* dst0 = dstb + ((size_t)(b0 * HH + h) * TT + tq0 + lrow) * QKD + lchk * 8;
    const u16* src0 = myT + lrow * BSTR + lchk * 8;
    #pragma unroll
    for (int x = 0; x < 8; x++)
        *(short8*)(dst0 + (size_t)x * 8 * QKD) = *(const short8*)(src0 + x * 8 * BSTR);
}

// ---------------------------------------------------------------------------
// Output projection GEMM: attn_b[M,K] bf16 @ Wo_t[N,K]^T + bo -> out fp32
// ---------------------------------------------------------------------------
__global__ __launch_bounds__(256) void out_gemm(
    const u16* __restrict__ A, const u16* __restrict__ Bt,
    const float* __restrict__ bo, float* __restrict__ out)
{
    __shared__ u16 As[128 * 64];
    __shared__ u16 Bs[128 * 64];

    const int m0 = blockIdx.y * 128, n0 = blockIdx.x * 128;

    float4v acc[4][4];
    #pragma unroll
    for (int i = 0; i < 4; i++)
        #pragma unroll
        for (int j = 0; j < 4; j++) acc[i][j] = (float4v){0.f, 0.f, 0.f, 0.f};

    gemm_mainloop(A, Bt, m0, n0, As, Bs, acc);

    const int lane = threadIdx.x & 63, wave = threadIdx.x >> 6;
    const int l15 = lane & 15, lg = lane >> 4;
    const int wm = wave >> 1, wn = wave & 1;
    const int mbase = m0 + wm * 64;
    const int nbase = n0 + wn * 64;

    float bov[4];
    #pragma unroll
    for (int nj = 0; nj < 4; nj++) bov[nj] = bo[nbase + nj * 16 + l15];

    #pragma unroll
    for (int mi = 0; mi < 4; mi++)
        #pragma unroll
        for (int r = 0; r < 4; r++) {
            const int m = mbase + mi * 16 + lg * 4 + r;
            float* op = out + (size_t)m * NN + nbase + l15;
            #pragma unroll
            for (int nj = 0; nj < 4; nj++)
                op[nj * 16] = acc[mi][nj][r] + bov[nj];
        }
}

// ---------------------------------------------------------------------------
// MFMA flash attention, causal, paired Q-tiles, TRANSPOSED-S formulation:
//   S^T = K·Q^T  (C rows=key, cols=query=lane&15)
//   O^T = V^T·P^T (C rows=d,  cols=query)
// Wins vs round-7: softmax reduce = in-register tree + 2 shuffles (was 4);
// K A-fragments are query-independent -> loaded straight from global into
// registers once per iter (Ks LDS array deleted; LDS 27.6 -> 18.4 KB);
// m/l state is one scalar per lane.
// ---------------------------------------------------------------------------
#define LSTR 72

__global__ __launch_bounds__(256, 4) void attn_mfma(
    const u16* __restrict__ qh, const u16* __restrict__ kh,
    const u16* __restrict__ vh, const float* __restrict__ head_scale,
    u16* __restrict__ out)
{
    __shared__ u16 Vs[64 * LSTR];      // V tile transposed [d][key]
    __shared__ u16 Ps[4][16 * LSTR];   // per-wave P^T round-trip [q][key]

    const int b = blockIdx.z, h = blockIdx.y, pi = blockIdx.x;
    const int t0L = pi * 64, t0H = (31 - pi) * 64;
    const int tid  = threadIdx.x;
    const int wave = tid >> 6, lane = tid & 63;
    const int l15 = lane & 15, lg = lane >> 4;

    const size_t bh_off = (size_t)(b * HH + h) * TT * QKD;
    const u16* qbh = qh + bh_off;
    const u16* kbh = kh + bh_off;
    const u16* vbh = vh + bh_off;

    // Q fragments (B-operand: n=q=lane&15, k=d=lg*8+j) — same loads as before
    short8 qfL[2], qfH[2];
    #pragma unroll
    for (int kc = 0; kc < 2; kc++) {
        qfL[kc] = *(const short8*)(qbh + (size_t)(t0L + wave * 16 + l15) * QKD + kc * 32 + lg * 8);
        qfH[kc] = *(const short8*)(qbh + (size_t)(t0H + wave * 16 + l15) * QKD + kc * 32 + lg * 8);
    }

    float4v oL[4], oH[4];                 // O^T tiles: [mi] rows d, cols q
    #pragma unroll
    for (int mi = 0; mi < 4; mi++) {
        oL[mi] = (float4v){0.f, 0.f, 0.f, 0.f};
        oH[mi] = (float4v){0.f, 0.f, 0.f, 0.f};
    }
    float mLs = -INFINITY, mHs = -INFINITY;   // per-lane (per-query) scalars
    float lLs = 0.f, lHs = 0.f;

    u16* pw = Ps[wave];
    short8 kf[2][4];   // K A-fragments [kc][nt], wave-uniform, from global

    auto process = [&](const short8 (&qf)[2], float4v (&o_acc)[4],
                       float& m_run, float& l_run, int t0, int j0) {
        // S^T tiles: sarr[nt] rows key = nt*16+lg*4+r, col q = l15
        float4v sarr[4];
        #pragma unroll
        for (int nt = 0; nt < 4; nt++) {
            float4v s = (float4v){0.f, 0.f, 0.f, 0.f};
            #pragma unroll
            for (int kc = 0; kc < 2; kc++)
                s = __builtin_amdgcn_mfma_f32_16x16x32_bf16(kf[kc][nt], qf[kc], s, 0, 0, 0);
            sarr[nt] = s;
        }

        if (j0 == t0) {   // diagonal tile: causal mask (key > query)
            const int qcol = t0 + wave * 16 + l15;
            #pragma unroll
            for (int nt = 0; nt < 4; nt++) {
                #pragma unroll
                for (int r = 0; r < 4; r++)
                    if (j0 + nt * 16 + lg * 4 + r > qcol) sarr[nt][r] = -INFINITY;
            }
        }

        // max over this lane's 16 keys (register tree) + 2 shuffles over lg
        float mt = -INFINITY;
        #pragma unroll
        for (int nt = 0; nt < 4; nt++)
            #pragma unroll
            for (int r = 0; r < 4; r++) mt = fmaxf(mt, sarr[nt][r]);
        mt = fmaxf(mt, __shfl_xor(mt, 16));
        mt = fmaxf(mt, __shfl_xor(mt, 32));
        float m_new = fmaxf(m_run, mt);
        float alpha = exp2f(m_run - m_new);   // first tile: exp2(-inf)=0
        float ps = 0.f;
        #pragma unroll
        for (int nt = 0; nt < 4; nt++) {
            #pragma unroll
            for (int r = 0; r < 4; r++) {
                float p = exp2f(sarr[nt][r] - m_new);
                ps += p;
                pw[l15 * LSTR + nt * 16 + lg * 4 + r] = f2bf(p);
            }
        }
        ps += __shfl_xor(ps, 16);
        ps += __shfl_xor(ps, 32);
        l_run = l_run * alpha + ps;
        m_run = m_new;
        #pragma unroll
        for (int mi = 0; mi < 4; mi++)
            #pragma unroll
            for (int r = 0; r < 4; r++) o_acc[mi][r] *= alpha;

        // P^T B-fragments: lane q=l15 holds P[q][kc*32+lg*8 ..+8]
        short8 pf[2];
        #pragma unroll
        for (int kc = 0; kc < 2; kc++)
            pf[kc] = *(const short8*)&pw[l15 * LSTR + kc * 32 + lg * 8];
        // O^T += V^T · P^T   (A = V^T rows: m=d=l15, k=key)
        #pragma unroll
        for (int mi = 0; mi < 4; mi++) {
            #pragma unroll
            for (int kc = 0; kc < 2; kc++) {
                short8 vfrag = *(const short8*)&Vs[(mi * 16 + l15) * LSTR + kc * 32 + lg * 8];
                o_acc[mi] = __builtin_amdgcn_mfma_f32_16x16x32_bf16(vfrag, pf[kc], o_acc[mi], 0, 0, 0);
            }
        }
    };

    for (int j0 = 0; j0 <= t0H; j0 += 64) {
        // K A-fragments straight from global (rows of K[key][d]); coalesced
        #pragma unroll
        for (int nt = 0; nt < 4; nt++)
            #pragma unroll
            for (int kc = 0; kc < 2; kc++)
                kf[kc][nt] = *(const short8*)(kbh + (size_t)(j0 + nt * 16 + l15) * QKD + kc * 32 + lg * 8);

        // stage V transposed [d][key] (scalar LDS writes)
        #pragma unroll
        for (int r = 0; r < 2; r++) {
            int j   = tid & 63;
            int dv0 = (tid >> 6) * 8 + r * 32;
            short8 v8 = *(const short8*)(vbh + (size_t)(j0 + j) * QKD + dv0);
            #pragma unroll
            for (int i = 0; i < 8; i++)
                Vs[(dv0 + i) * LSTR + j] = (u16)v8[i];
        }
        __syncthreads();

        process(qfH, oH, mHs, lHs, t0H, j0);
        if (j0 <= t0L) process(qfL, oL, mLs, lLs, t0L, j0);
        __syncthreads();
    }

    // epilogue: transpose O^T -> [q][d] through pw, full-line stores
    const float hs = 1.0f + head_scale[h];
    auto writeback = [&](const float4v (&o_acc)[4], float l_run, int t0) {
        const float f = hs / l_run;
        #pragma unroll
        for (int mi = 0; mi < 4; mi++)
            #pragma unroll
            for (int r = 0; r < 4; r++)
                pw[l15 * LSTR + mi * 16 + lg * 4 + r] = f2bf(o_acc[mi][r] * f);
        // 16 q-rows x 128B; 8 lanes/row, 1 b128 each, 2 passes
        #pragma unroll
        for (int pass = 0; pass < 2; pass++) {
            const int qrow = (lane >> 3) + pass * 8;
            const int ch = (lane & 7) * 8;
            const int q = t0 + wave * 16 + qrow;
            u16* op = out + ((size_t)(b * TT + q) * NN) + h * QKD + ch;
            *(short8*)op = *(const short8*)&pw[qrow * LSTR + ch];
        }
    };
    writeback(oL, lLs, t0L);
    writeback(oH, lHs, t0H);
}

// ---------------------------------------------------------------------------
extern "C" void kernel_launch(void* const* d_in, const int* in_sizes, int n_in,
                              void* d_out, int out_size, void* d_ws, size_t ws_size,
                              hipStream_t stream)
{
    const float* q          = (const float*)d_in[0];
    const float* kv         = (const float*)d_in[1];
    /* d_in[2] = causal mask -- handled analytically */
    const int*   qpos       = (const int*)d_in[3];
    const int*   kpos       = (const int*)d_in[4];
    const float* Wq         = (const float*)d_in[5];
    const float* bq         = (const float*)d_in[6];
    const float* Wk         = (const float*)d_in[7];
    const float* bk         = (const float*)d_in[8];
    const float* Wv         = (const float*)d_in[9];
    const float* bv         = (const float*)d_in[10];
    const float* q_scale    = (const float*)d_in[11];
    const float* k_scale    = (const float*)d_in[12];
    const float* head_scale = (const float*)d_in[13];
    const float* Wo         = (const float*)d_in[14];
    const float* bo         = (const float*)d_in[15];
    float* out = (float*)d_out;

    char* ws = (char*)d_ws;
    u16* qb     = (u16*)(ws);
    u16* kvb    = (u16*)(ws + (16u << 20));
    u16* Wt     = (u16*)(ws + (32u << 20));
    u16* qh_b   = (u16*)(ws + (40u << 20));
    u16* kh_b   = (u16*)(ws + (56u << 20));
    u16* vh_b   = (u16*)(ws + (72u << 20));
    u16* attn_b = (u16*)(ws + (88u << 20));

    acast_kernel<<<dim3(MM * DD / (256 * 4), 2), 256, 0, stream>>>(q, kv, qb, kvb);
    wt_kernel<<<dim3(16, 16, 4), 256, 0, stream>>>(Wq, Wk, Wv, Wo, Wt);
    // z split into 3 dispatches: per-z FETCH/WRITE discriminates the
    // 1.5 GB write mystery (external bleed -> all on z=0; kernel -> even)
    for (int z = 0; z < 3; z++)
        qkv_gemm<<<dim3(NN / 128, MM / 128), 256, 0, stream>>>(
            qb, kvb, Wt, bq, bk, bv, qpos, kpos, q_scale, k_scale,
            qh_b, kh_b, vh_b, z);
    attn_mfma<<<dim3(16, HH, BB), 256, 0, stream>>>(qh_b, kh_b, vh_b, head_scale, attn_b);
    out_gemm<<<dim3(NN / 128, MM / 128), 256, 0, stream>>>(attn_b, Wt + (size_t)3 * KK * NN, bo, out);
}